// Round 1
// baseline (287.073 us; speedup 1.0000x reference)
//
#include <hip/hip_runtime.h>
#include <math.h>

typedef unsigned short u16;
typedef __attribute__((ext_vector_type(8))) short short8;
typedef __attribute__((ext_vector_type(8))) u16 u16x8;
typedef __attribute__((ext_vector_type(4))) float f32x4;

// round-to-nearest-even f32 -> bf16 bits
static __device__ __forceinline__ u16 f2bf(float x) {
  unsigned u = __builtin_bit_cast(unsigned, x);
  return (u16)((u + 0x7FFFu + ((u >> 16) & 1u)) >> 16);
}

// ---------------- K1: frequency response k[c,f], c<512, f<2048 ----------------
// k[c,f] = K[c,f] (f<1024) or K[c+512, 2047-f] (f>=1024)
// K[h,l] = sum_n (Hr+iHi)[h,n] * exp(-i*theta(h,l)*(n+1))
__global__ __launch_bounds__(256) void build_k(
    const float* __restrict__ log_dt, const float* __restrict__ Hr,
    const float* __restrict__ Hi, float* __restrict__ kr, float* __restrict__ ki) {
  const int f = blockIdx.x * 256 + threadIdx.x;  // 0..2047
  const int c = blockIdx.y;                      // 0..511
  int h, l;
  if (f < 1024) { h = c; l = f; } else { h = c + 512; l = 2047 - f; }
  const float dt = expf(log_dt[h]);
  const float phi = 6.28318530717958647692f * (float)l * (1.0f / 1024.0f);
  float sphi, cphi;
  sincosf(phi, &sphi, &cphi);
  const float nr = (1.f + dt) * cphi + dt - 1.f;
  const float ni = (1.f + dt) * sphi;
  const float dr = (dt - 1.f) * cphi + dt + 1.f;
  const float di = (dt - 1.f) * sphi;
  const float theta = atan2f(ni * dr - nr * di, nr * dr + ni * di);
  float sw, cw;
  sincosf(theta, &sw, &cw);
  const float wr = cw, wi = -sw;      // e^{-i theta}
  float cr = wr, ci = wi;             // e^{-i theta * (n+1)}, n=0
  float ar = 0.f, ai = 0.f;
  const float* __restrict__ hr = Hr + h * 64;
  const float* __restrict__ hi = Hi + h * 64;
  for (int n = 0; n < 64; ++n) {
    const float a = hr[n], bb = hi[n];
    ar += a * cr - bb * ci;
    ai += a * ci + bb * cr;
    const float t = cr * wr - ci * wi;
    ci = cr * wi + ci * wr;
    cr = t;
  }
  kr[c * 2048 + f] = ar;
  ki[c * 2048 + f] = ai;
}

// ---------------- K2: per-row FFT conv + D-skip + GELU -> bf16 y ----------------
// Stockham radix-2 DIF, 2048 points, ping-pong LDS. Natural-order output.
static __device__ __forceinline__ void fft11(float*& sr, float*& si,
                                             float*& dr, float*& di, int tid) {
  #pragma unroll 1
  for (int s = 0; s < 11; ++s) {
    const int m = 1 << s;
    const int l = 1024 >> s;
    #pragma unroll
    for (int q = 0; q < 4; ++q) {
      const int idx = tid + q * 256;      // butterfly 0..1023
      const int j = idx >> s;             // 0..l-1
      float sw, cw;
      __sincosf(-3.14159265358979323846f * (float)j / (float)l, &sw, &cw);
      const float x0r = sr[idx],        x0i = si[idx];
      const float x1r = sr[idx + 1024], x1i = si[idx + 1024];
      const int o = idx + j * m;          // = kk + 2*j*m
      dr[o] = x0r + x1r;  di[o] = x0i + x1i;
      const float odr = x0r - x1r, odi = x0i - x1i;
      dr[o + m] = cw * odr - sw * odi;
      di[o + m] = cw * odi + sw * odr;
    }
    __syncthreads();
    float* t;
    t = sr; sr = dr; dr = t;
    t = si; si = di; di = t;
  }
}

__global__ __launch_bounds__(256) void fft_conv(
    const float* __restrict__ u, const float* __restrict__ kr,
    const float* __restrict__ ki, const float* __restrict__ Dv,
    u16* __restrict__ y) {
  __shared__ float Ar[2048], Ai[2048], Br[2048], Bi[2048];  // 32 KB
  const int b = blockIdx.x, c = blockIdx.y;
  const int tid = threadIdx.x;
  const float* __restrict__ urow = u + ((size_t)(b * 512 + c)) * 2048;
  float ur[8];
  {
    const float4 v0 = ((const float4*)urow)[tid * 2];
    const float4 v1 = ((const float4*)urow)[tid * 2 + 1];
    ur[0] = v0.x; ur[1] = v0.y; ur[2] = v0.z; ur[3] = v0.w;
    ur[4] = v1.x; ur[5] = v1.y; ur[6] = v1.z; ur[7] = v1.w;
    #pragma unroll
    for (int i = 0; i < 8; ++i) { Ar[tid * 8 + i] = ur[i]; Ai[tid * 8 + i] = 0.f; }
  }
  __syncthreads();
  float *sr = Ar, *si = Ai, *dr = Br, *di = Bi;
  fft11(sr, si, dr, di, tid);                 // forward FFT of u
  #pragma unroll
  for (int q = 0; q < 8; ++q) {               // X *= k[c,:], then conjugate
    const int f = tid + q * 256;
    const float xr = sr[f], xi = si[f];
    const float krv = kr[c * 2048 + f], kiv = ki[c * 2048 + f];
    sr[f] = xr * krv - xi * kiv;
    si[f] = -(xr * kiv + xi * krv);
  }
  __syncthreads();
  fft11(sr, si, dr, di, tid);                 // ifft via conj trick; Re = Re(result)/N
  const float Dc = Dv[c];
  u16 ov[8];
  #pragma unroll
  for (int i = 0; i < 8; ++i) {
    const int t = tid * 8 + i;
    const float yv = sr[t] * (1.0f / 2048.0f) + ur[i] * Dc;
    const float g = 0.5f * yv * (1.0f + erff(yv * 0.70710678118654752440f)); // exact GELU
    ov[i] = f2bf(g);
  }
  *(u16x8*)(y + ((size_t)(b * 512 + c)) * 2048 + tid * 8) = *(u16x8*)ov;
}

// ---------------- K2b: y (B,C,L) bf16 -> yt (B,L,C) bf16 ----------------
__global__ __launch_bounds__(256) void transpose_y(
    const u16* __restrict__ y, u16* __restrict__ yt) {
  __shared__ u16 tile[64][80];
  const int b = blockIdx.z;
  const int tb = blockIdx.x * 64;
  const int cb = blockIdx.y * 64;
  const int tid = threadIdx.x;
  {
    const int tl = (tid & 7) * 8;
    const int cl = tid >> 3;  // 0..31
    #pragma unroll
    for (int h = 0; h < 2; ++h) {
      const int cc = cl + h * 32;
      const u16x8 v = *(const u16x8*)(y + ((size_t)(b * 512 + cb + cc)) * 2048 + tb + tl);
      #pragma unroll
      for (int i = 0; i < 8; ++i) tile[cc][tl + i] = v[i];
    }
  }
  __syncthreads();
  {
    const int c2 = (tid & 7) * 8;
    const int t2 = tid >> 3;  // 0..31
    #pragma unroll
    for (int h = 0; h < 2; ++h) {
      const int tt = t2 + h * 32;
      u16 tmp[8];
      #pragma unroll
      for (int i = 0; i < 8; ++i) tmp[i] = tile[c2 + i][tt];
      *(u16x8*)(yt + ((size_t)(b * 2048 + tb + tt)) * 512 + cb + c2) = *(u16x8*)tmp;
    }
  }
}

// ---------------- K2c: W f32 -> bf16 ----------------
__global__ __launch_bounds__(256) void conv_w(const float* __restrict__ W,
                                              u16* __restrict__ Wb) {
  const int i = blockIdx.x * 256 + threadIdx.x;  // grid covers 1024*512 exactly
  Wb[i] = f2bf(W[i]);
}

// ---------------- K3: z = W*y + b, out = a * sigmoid(g) ----------------
// A-stack interleaves a/g rows: stack row r -> W row (r&1 ? 512+m0+r/2 : m0+r/2),
// so GLU pairing is intra-lane (C/D regs 0/1 and 2/3 are adjacent rows).
__global__ __launch_bounds__(256) void gemm_glu(
    const u16* __restrict__ Wb, const u16* __restrict__ yt,
    const float* __restrict__ bias, float* __restrict__ out) {
  __shared__ __align__(16) u16 Alds[128 * 40];  // [stack row][k], pad to 40 (80B stride)
  __shared__ __align__(16) u16 Blds[128 * 40];  // [t row][k]
  const int b = blockIdx.z;
  const int m0 = blockIdx.y * 64;   // output-channel base (64 channels/tile)
  const int t0 = blockIdx.x * 128;
  const int tid = threadIdx.x;
  const int lane = tid & 63, wid = tid >> 6;
  const int wm = wid >> 1, wn = wid & 1;        // 2x2 waves, 64x64 each
  const int lrow = lane & 15, lk = (lane >> 4) * 8;

  f32x4 acc[4][4];
  const f32x4 z4 = {0.f, 0.f, 0.f, 0.f};
  #pragma unroll
  for (int mi = 0; mi < 4; ++mi)
    #pragma unroll
    for (int ni = 0; ni < 4; ++ni) acc[mi][ni] = z4;

  for (int kk = 0; kk < 512; kk += 32) {
    __syncthreads();
    #pragma unroll
    for (int q = 0; q < 2; ++q) {
      const int li = tid + q * 256;
      const int r = li >> 2;            // 0..127
      const int kc = (li & 3) * 8;      // 0,8,16,24
      const int o = (r & 1) ? (512 + m0 + (r >> 1)) : (m0 + (r >> 1));
      *(u16x8*)&Alds[r * 40 + kc] = *(const u16x8*)(Wb + (size_t)o * 512 + kk + kc);
      *(u16x8*)&Blds[r * 40 + kc] =
          *(const u16x8*)(yt + ((size_t)(b * 2048 + t0 + r)) * 512 + kk + kc);
    }
    __syncthreads();
    short8 af[4], bf[4];
    #pragma unroll
    for (int mi = 0; mi < 4; ++mi)
      af[mi] = __builtin_bit_cast(short8,
               *(const u16x8*)&Alds[(wm * 64 + mi * 16 + lrow) * 40 + lk]);
    #pragma unroll
    for (int ni = 0; ni < 4; ++ni)
      bf[ni] = __builtin_bit_cast(short8,
               *(const u16x8*)&Blds[(wn * 64 + ni * 16 + lrow) * 40 + lk]);
    #pragma unroll
    for (int mi = 0; mi < 4; ++mi)
      #pragma unroll
      for (int ni = 0; ni < 4; ++ni)
        acc[mi][ni] = __builtin_amdgcn_mfma_f32_16x16x32_bf16(af[mi], bf[ni],
                                                              acc[mi][ni], 0, 0, 0);
  }

  const int rsub = (lane >> 4) * 4;  // C/D: row = (lane>>4)*4 + reg, col = lane&15
  #pragma unroll
  for (int mi = 0; mi < 4; ++mi) {
    const int rbase = wm * 64 + mi * 16 + rsub;  // even, multiple of 4
    const int ch = m0 + (rbase >> 1);
    const float ba0 = bias[ch],     bg0 = bias[512 + ch];
    const float ba1 = bias[ch + 1], bg1 = bias[512 + ch + 1];
    #pragma unroll
    for (int ni = 0; ni < 4; ++ni) {
      const int t = t0 + wn * 64 + ni * 16 + (lane & 15);
      const f32x4 v = acc[mi][ni];
      const float a0 = v[0] + ba0, g0 = v[1] + bg0;
      const float a1 = v[2] + ba1, g1 = v[3] + bg1;
      out[((size_t)(b * 512 + ch)) * 2048 + t]     = a0 / (1.f + expf(-g0));
      out[((size_t)(b * 512 + ch + 1)) * 2048 + t] = a1 / (1.f + expf(-g1));
    }
  }
}

extern "C" void kernel_launch(void* const* d_in, const int* in_sizes, int n_in,
                              void* d_out, int out_size, void* d_ws, size_t ws_size,
                              hipStream_t stream) {
  (void)in_sizes; (void)n_in; (void)out_size; (void)ws_size;
  const float* u      = (const float*)d_in[0];
  const float* log_dt = (const float*)d_in[1];
  const float* Hr     = (const float*)d_in[2];
  const float* Hi     = (const float*)d_in[3];
  const float* Dv     = (const float*)d_in[4];
  const float* W      = (const float*)d_in[5];
  const float* bias   = (const float*)d_in[6];

  char* ws = (char*)d_ws;
  float* kr = (float*)(ws);                         // 4 MB
  float* ki = (float*)(ws + ((size_t)4 << 20));     // 4 MB
  u16*   Wb = (u16*)  (ws + ((size_t)8 << 20));     // 1 MB
  u16*   yt = (u16*)  (ws + ((size_t)10 << 20));    // 32 MB -> total 42 MB
  u16*   ybf = (u16*)d_out;                         // bf16 y staged in d_out (32 MB of 64)

  build_k<<<dim3(8, 512), 256, 0, stream>>>(log_dt, Hr, Hi, kr, ki);
  conv_w<<<dim3(2048), 256, 0, stream>>>(W, Wb);
  fft_conv<<<dim3(16, 512), 256, 0, stream>>>(u, kr, ki, Dv, ybf);
  transpose_y<<<dim3(32, 8, 16), 256, 0, stream>>>(ybf, yt);
  gemm_glu<<<dim3(16, 8, 16), 256, 0, stream>>>(Wb, yt, bias, (float*)d_out);
}

// Round 2
// 158.745 us; speedup vs baseline: 1.8084x; 1.8084x over previous
//
#include <hip/hip_runtime.h>
#include <math.h>

typedef unsigned short u16;
typedef __attribute__((ext_vector_type(8))) short short8;
typedef __attribute__((ext_vector_type(8))) u16 u16x8;
typedef __attribute__((ext_vector_type(4))) float f32x4;

#define PHYS(i) ((i) + ((i) >> 4))

static __device__ __forceinline__ u16 f2bf(float x) {
  unsigned u = __builtin_bit_cast(unsigned, x);
  return (u16)((u + 0x7FFFu + ((u >> 16) & 1u)) >> 16);
}

static __device__ __forceinline__ float2 cmul(float2 a, float2 b) {
  return make_float2(a.x * b.x - a.y * b.y, a.x * b.y + a.y * b.x);
}

// ---------------- K1: ke[c,q] = (k[c,q] + conj(k[c,(2048-q)%2048]))/2, q=0..1024
// k[c,f] = K[c,f] (f<1024) else K[c+512, 2047-f];  K = hope kernel.
static __device__ __forceinline__ void hope_sum(
    const float* __restrict__ log_dt, const float* __restrict__ Hr,
    const float* __restrict__ Hi, int h, int l, float* outr, float* outi) {
  const float dt = expf(log_dt[h]);
  const float phi = 6.28318530717958647692f * (float)l * (1.0f / 1024.0f);
  float sphi, cphi;
  sincosf(phi, &sphi, &cphi);
  const float nr = (1.f + dt) * cphi + dt - 1.f;
  const float ni = (1.f + dt) * sphi;
  const float dr = (dt - 1.f) * cphi + dt + 1.f;
  const float di = (dt - 1.f) * sphi;
  const float theta = atan2f(ni * dr - nr * di, nr * dr + ni * di);
  float sw, cw;
  sincosf(theta, &sw, &cw);
  const float wr = cw, wi = -sw;  // e^{-i theta}
  float cr = wr, ci = wi;
  float ar = 0.f, ai = 0.f;
  const float* __restrict__ hr = Hr + h * 64;
  const float* __restrict__ hi = Hi + h * 64;
  for (int n = 0; n < 64; ++n) {
    const float a = hr[n], bb = hi[n];
    ar += a * cr - bb * ci;
    ai += a * ci + bb * cr;
    const float t = cr * wr - ci * wi;
    ci = cr * wi + ci * wr;
    cr = t;
  }
  *outr = ar;
  *outi = ai;
}

__global__ __launch_bounds__(256) void build_ke(
    const float* __restrict__ log_dt, const float* __restrict__ Hr,
    const float* __restrict__ Hi, float2* __restrict__ ke) {
  const int q = blockIdx.x * 256 + threadIdx.x;  // 0..1279
  const int c = blockIdx.y;
  if (q > 1024) return;
  float s1r = 0.f, s1i = 0.f, s2r = 0.f, s2i = 0.f;
  if (q <= 1023) hope_sum(log_dt, Hr, Hi, c, q, &s1r, &s1i);        // k[c,q]
  if (q >= 1) hope_sum(log_dt, Hr, Hi, c + 512, q - 1, &s2r, &s2i); // k[c,2048-q]
  float kr, ki;
  if (q == 0)         { kr = s1r; ki = 0.f; }
  else if (q == 1024) { kr = s2r; ki = 0.f; }
  else                { kr = 0.5f * (s1r + s2r); ki = 0.5f * (s1i - s2i); }
  ke[c * 1026 + q] = make_float2(kr, ki);
}

// ---------------- radix-4 Stockham, 1024 pts, 256 threads, padded LDS ----------------
static __device__ __forceinline__ float2* fft1024(float2* S, float2* D, int tid,
                                                  const float2* __restrict__ tw) {
  #pragma unroll
  for (int t = 0; t < 5; ++t) {
    const int sh = 2 * t;
    const int m = 1 << sh;
    const int kk = tid & (m - 1);
    const int o = kk + ((tid >> sh) << (sh + 2));
    const float2 a = S[PHYS(tid)];
    const float2 b = S[PHYS(tid + 256)];
    const float2 c = S[PHYS(tid + 512)];
    const float2 d = S[PHYS(tid + 768)];
    const float apcr = a.x + c.x, apci = a.y + c.y;
    const float amcr = a.x - c.x, amci = a.y - c.y;
    const float bpdr = b.x + d.x, bpdi = b.y + d.y;
    const float bmdr = b.x - d.x, bmdi = b.y - d.y;
    const float2 y0 = make_float2(apcr + bpdr, apci + bpdi);
    const float2 y2 = make_float2(apcr - bpdr, apci - bpdi);
    const float2 y1 = make_float2(amcr + bmdi, amci - bmdr);  // amc - i(b-d)
    const float2 y3 = make_float2(amcr - bmdi, amci + bmdr);  // amc + i(b-d)
    const float2 w1 = tw[tid - kk];  // T[(tid>>sh)<<sh], T[m]=e^{-2pi i m/1024}
    const float2 w2 = cmul(w1, w1);
    const float2 w3 = cmul(w2, w1);
    D[PHYS(o)] = y0;
    D[PHYS(o + m)] = cmul(w1, y1);
    D[PHYS(o + 2 * m)] = cmul(w2, y2);
    D[PHYS(o + 3 * m)] = cmul(w3, y3);
    __syncthreads();
    float2* ts = S; S = D; D = ts;
  }
  return S;
}

// ---------------- K2: rfft-conv via 1024-pt packed FFT + D-skip + GELU -> bf16 y
__global__ __launch_bounds__(256) void fft_conv(
    const float* __restrict__ u, const float2* __restrict__ ke,
    const float* __restrict__ Dv, u16* __restrict__ y) {
  __shared__ float2 bufA[1088], bufB[1088], twl[256];
  const int b = blockIdx.x, c = blockIdx.y;
  const int tid = threadIdx.x;
  {
    float s, cc;
    sincosf(6.28318530717958647692f * (float)tid * (1.f / 1024.f), &s, &cc);
    twl[tid] = make_float2(cc, -s);
  }
  const float* __restrict__ urow = u + ((size_t)(b * 512 + c)) * 2048;
  float ur[8];
  {
    const float4 v0 = ((const float4*)urow)[tid * 2];
    const float4 v1 = ((const float4*)urow)[tid * 2 + 1];
    ur[0] = v0.x; ur[1] = v0.y; ur[2] = v0.z; ur[3] = v0.w;
    ur[4] = v1.x; ur[5] = v1.y; ur[6] = v1.z; ur[7] = v1.w;
  }
  #pragma unroll
  for (int j = 0; j < 4; ++j)
    bufA[PHYS(4 * tid + j)] = make_float2(ur[2 * j], ur[2 * j + 1]);  // z_t = u[2t]+i u[2t+1]
  __syncthreads();

  float2* Z = fft1024(bufA, bufB, tid, twl);
  float2* D = (Z == bufA) ? bufB : bufA;

  // pointwise: unpack rfft bins, multiply by ke, repack for inverse (conjugated)
  const float2* __restrict__ kerow = ke + c * 1026;
  #pragma unroll
  for (int j = 0; j < 2; ++j) {
    const int f = tid + 256 * j;
    if (f == 0) {
      const float2 Z0 = Z[PHYS(0)];
      const float2 ke0 = kerow[0], keN = kerow[1024];
      const float X0 = Z0.x + Z0.y;   // real bins
      const float XN = Z0.x - Z0.y;
      const float2 Y0 = make_float2(X0 * ke0.x, X0 * ke0.y);
      const float2 YN = make_float2(XN * keN.x, XN * keN.y);
      const float Pr = Y0.x + YN.x, Pi = Y0.y - YN.y;
      const float Qr = Y0.x - YN.x, Qi = Y0.y + YN.y;
      D[PHYS(0)] = make_float2(Pr - Qi, -(Pi + Qr));  // conj(Z'_0)
      const float2 Z5 = Z[PHYS(512)];
      const float2 X5 = make_float2(Z5.x, -Z5.y);
      const float2 Y5 = cmul(X5, kerow[512]);
      D[PHYS(512)] = make_float2(2.f * Y5.x, 2.f * Y5.y);  // conj(Z'_512)=2*Y5
    } else {
      const int g = 1024 - f;
      const float2 Zf = Z[PHYS(f)], Zg = Z[PHYS(g)];
      float st, ct;
      __sincosf(3.14159265358979323846f * (1.f / 1024.f) * (float)f, &st, &ct);
      const float Ar = 0.5f * (Zf.x + Zg.x), Ai = 0.5f * (Zf.y - Zg.y);
      const float Br = 0.5f * (Zf.x - Zg.x), Bi = 0.5f * (Zf.y + Zg.y);
      const float Cr = ct * Bi - st * Br, Ci = -(ct * Br + st * Bi);
      const float2 Xf = make_float2(Ar + Cr, Ai + Ci);
      const float2 Xg = make_float2(Ar - Cr, Ci - Ai);
      const float2 Yf = cmul(Xf, kerow[f]);
      const float2 Yg = cmul(Xg, kerow[g]);
      const float Pr = Yf.x + Yg.x, Pi = Yf.y - Yg.y;
      const float Qr = Yf.x - Yg.x, Qi = Yf.y + Yg.y;
      const float Rr = -(ct * Qi + st * Qr), Ri = ct * Qr - st * Qi;
      D[PHYS(f)] = make_float2(Pr + Rr, -(Pi + Ri));   // conj(Z'_f)
      D[PHYS(g)] = make_float2(Pr - Rr, -(Ri - Pi));   // conj(Z'_g)
    }
  }
  __syncthreads();

  float2* R = fft1024(D, Z, tid, twl);  // ifft via conj trick

  const float Dc = Dv[c];
  u16 ov[8];
  #pragma unroll
  for (int j = 0; j < 4; ++j) {
    const float2 r = R[PHYS(4 * tid + j)];
    const float ye = r.x * (1.f / 2048.f) + ur[2 * j] * Dc;
    const float yo = -r.y * (1.f / 2048.f) + ur[2 * j + 1] * Dc;
    const float ge = 0.5f * ye * (1.f + erff(ye * 0.70710678118654752440f));
    const float go = 0.5f * yo * (1.f + erff(yo * 0.70710678118654752440f));
    ov[2 * j] = f2bf(ge);
    ov[2 * j + 1] = f2bf(go);
  }
  *(u16x8*)(y + ((size_t)(b * 512 + c)) * 2048 + tid * 8) = *(u16x8*)ov;
}

// ---------------- K2b: y (B,C,L) bf16 -> yt (B,L,C) bf16 ----------------
__global__ __launch_bounds__(256) void transpose_y(
    const u16* __restrict__ y, u16* __restrict__ yt) {
  __shared__ u16 tile[64][80];
  const int b = blockIdx.z;
  const int tb = blockIdx.x * 64;
  const int cb = blockIdx.y * 64;
  const int tid = threadIdx.x;
  {
    const int tl = (tid & 7) * 8;
    const int cl = tid >> 3;
    #pragma unroll
    for (int h = 0; h < 2; ++h) {
      const int cc = cl + h * 32;
      const u16x8 v = *(const u16x8*)(y + ((size_t)(b * 512 + cb + cc)) * 2048 + tb + tl);
      #pragma unroll
      for (int i = 0; i < 8; ++i) tile[cc][tl + i] = v[i];
    }
  }
  __syncthreads();
  {
    const int c2 = (tid & 7) * 8;
    const int t2 = tid >> 3;
    #pragma unroll
    for (int h = 0; h < 2; ++h) {
      const int tt = t2 + h * 32;
      u16 tmp[8];
      #pragma unroll
      for (int i = 0; i < 8; ++i) tmp[i] = tile[c2 + i][tt];
      *(u16x8*)(yt + ((size_t)(b * 2048 + tb + tt)) * 512 + cb + c2) = *(u16x8*)tmp;
    }
  }
}

// ---------------- K2c: W f32 -> bf16 ----------------
__global__ __launch_bounds__(256) void conv_w(const float* __restrict__ W,
                                              u16* __restrict__ Wb) {
  const int i = blockIdx.x * 256 + threadIdx.x;
  Wb[i] = f2bf(W[i]);
}

// ---------------- K3: z = W*y + b, out = a * sigmoid(g) ----------------
__global__ __launch_bounds__(256) void gemm_glu(
    const u16* __restrict__ Wb, const u16* __restrict__ yt,
    const float* __restrict__ bias, float* __restrict__ out) {
  __shared__ __align__(16) u16 Alds[128 * 40];
  __shared__ __align__(16) u16 Blds[128 * 40];
  const int b = blockIdx.z;
  const int m0 = blockIdx.y * 64;
  const int t0 = blockIdx.x * 128;
  const int tid = threadIdx.x;
  const int lane = tid & 63, wid = tid >> 6;
  const int wm = wid >> 1, wn = wid & 1;
  const int lrow = lane & 15, lk = (lane >> 4) * 8;

  f32x4 acc[4][4];
  const f32x4 z4 = {0.f, 0.f, 0.f, 0.f};
  #pragma unroll
  for (int mi = 0; mi < 4; ++mi)
    #pragma unroll
    for (int ni = 0; ni < 4; ++ni) acc[mi][ni] = z4;

  for (int kk = 0; kk < 512; kk += 32) {
    __syncthreads();
    #pragma unroll
    for (int q = 0; q < 2; ++q) {
      const int li = tid + q * 256;
      const int r = li >> 2;
      const int kc = (li & 3) * 8;
      const int o = (r & 1) ? (512 + m0 + (r >> 1)) : (m0 + (r >> 1));
      *(u16x8*)&Alds[r * 40 + kc] = *(const u16x8*)(Wb + (size_t)o * 512 + kk + kc);
      *(u16x8*)&Blds[r * 40 + kc] =
          *(const u16x8*)(yt + ((size_t)(b * 2048 + t0 + r)) * 512 + kk + kc);
    }
    __syncthreads();
    short8 af[4], bf[4];
    #pragma unroll
    for (int mi = 0; mi < 4; ++mi)
      af[mi] = __builtin_bit_cast(short8,
               *(const u16x8*)&Alds[(wm * 64 + mi * 16 + lrow) * 40 + lk]);
    #pragma unroll
    for (int ni = 0; ni < 4; ++ni)
      bf[ni] = __builtin_bit_cast(short8,
               *(const u16x8*)&Blds[(wn * 64 + ni * 16 + lrow) * 40 + lk]);
    #pragma unroll
    for (int mi = 0; mi < 4; ++mi)
      #pragma unroll
      for (int ni = 0; ni < 4; ++ni)
        acc[mi][ni] = __builtin_amdgcn_mfma_f32_16x16x32_bf16(af[mi], bf[ni],
                                                              acc[mi][ni], 0, 0, 0);
  }

  const int rsub = (lane >> 4) * 4;
  #pragma unroll
  for (int mi = 0; mi < 4; ++mi) {
    const int rbase = wm * 64 + mi * 16 + rsub;
    const int ch = m0 + (rbase >> 1);
    const float ba0 = bias[ch],     bg0 = bias[512 + ch];
    const float ba1 = bias[ch + 1], bg1 = bias[512 + ch + 1];
    #pragma unroll
    for (int ni = 0; ni < 4; ++ni) {
      const int t = t0 + wn * 64 + ni * 16 + (lane & 15);
      const f32x4 v = acc[mi][ni];
      const float a0 = v[0] + ba0, g0 = v[1] + bg0;
      const float a1 = v[2] + ba1, g1 = v[3] + bg1;
      out[((size_t)(b * 512 + ch)) * 2048 + t]     = a0 / (1.f + expf(-g0));
      out[((size_t)(b * 512 + ch + 1)) * 2048 + t] = a1 / (1.f + expf(-g1));
    }
  }
}

extern "C" void kernel_launch(void* const* d_in, const int* in_sizes, int n_in,
                              void* d_out, int out_size, void* d_ws, size_t ws_size,
                              hipStream_t stream) {
  (void)in_sizes; (void)n_in; (void)out_size; (void)ws_size;
  const float* u      = (const float*)d_in[0];
  const float* log_dt = (const float*)d_in[1];
  const float* Hr     = (const float*)d_in[2];
  const float* Hi     = (const float*)d_in[3];
  const float* Dv     = (const float*)d_in[4];
  const float* W      = (const float*)d_in[5];
  const float* bias   = (const float*)d_in[6];

  char* ws = (char*)d_ws;
  float2* ke = (float2*)(ws);                      // 512*1026*8 = 4.2 MB
  u16*    Wb = (u16*)  (ws + ((size_t)5 << 20));   // 1 MB
  u16*    yt = (u16*)  (ws + ((size_t)8 << 20));   // 32 MB
  u16*    ybf = (u16*)d_out;                       // bf16 y staged in d_out

  build_ke<<<dim3(5, 512), 256, 0, stream>>>(log_dt, Hr, Hi, ke);
  conv_w<<<dim3(2048), 256, 0, stream>>>(W, Wb);
  fft_conv<<<dim3(16, 512), 256, 0, stream>>>(u, ke, Dv, ybf);
  transpose_y<<<dim3(32, 8, 16), 256, 0, stream>>>(ybf, yt);
  gemm_glu<<<dim3(16, 8, 16), 256, 0, stream>>>(Wb, yt, bias, (float*)d_out);
}

// Round 3
// 153.798 us; speedup vs baseline: 1.8666x; 1.0322x over previous
//
#include <hip/hip_runtime.h>
#include <math.h>

typedef unsigned short u16;
typedef unsigned int u32;
typedef __attribute__((ext_vector_type(8))) short short8;
typedef __attribute__((ext_vector_type(8))) u16 u16x8;
typedef __attribute__((ext_vector_type(4))) float f32x4;

#define PHYS(i) ((i) + ((i) >> 4))

static __device__ __forceinline__ u16 f2bf(float x) {
  unsigned u = __builtin_bit_cast(unsigned, x);
  return (u16)((u + 0x7FFFu + ((u >> 16) & 1u)) >> 16);
}

static __device__ __forceinline__ float2 cmul(float2 a, float2 b) {
  return make_float2(a.x * b.x - a.y * b.y, a.x * b.y + a.y * b.x);
}

// async global->LDS, 16B per lane; dest = wave-uniform base + lane*16
static __device__ __forceinline__ void gload_lds16(const void* g, void* l) {
  __builtin_amdgcn_global_load_lds(
      (const __attribute__((address_space(1))) u32*)g,
      (__attribute__((address_space(3))) u32*)l, 16, 0, 0);
}

// ---------------- K1: ke[c,q] = (k[c,q] + conj(k[c,(2048-q)%2048]))/2, q=0..1024
static __device__ __forceinline__ void hope_sum(
    const float* __restrict__ log_dt, const float* __restrict__ Hr,
    const float* __restrict__ Hi, int h, int l, float* outr, float* outi) {
  const float dt = expf(log_dt[h]);
  const float phi = 6.28318530717958647692f * (float)l * (1.0f / 1024.0f);
  float sphi, cphi;
  sincosf(phi, &sphi, &cphi);
  const float nr = (1.f + dt) * cphi + dt - 1.f;
  const float ni = (1.f + dt) * sphi;
  const float dr = (dt - 1.f) * cphi + dt + 1.f;
  const float di = (dt - 1.f) * sphi;
  const float theta = atan2f(ni * dr - nr * di, nr * dr + ni * di);
  float sw, cw;
  sincosf(theta, &sw, &cw);
  const float wr = cw, wi = -sw;  // e^{-i theta}
  float cr = wr, ci = wi;
  float ar = 0.f, ai = 0.f;
  const float* __restrict__ hr = Hr + h * 64;
  const float* __restrict__ hi = Hi + h * 64;
  for (int n = 0; n < 64; ++n) {
    const float a = hr[n], bb = hi[n];
    ar += a * cr - bb * ci;
    ai += a * ci + bb * cr;
    const float t = cr * wr - ci * wi;
    ci = cr * wi + ci * wr;
    cr = t;
  }
  *outr = ar;
  *outi = ai;
}

__global__ __launch_bounds__(256) void build_ke(
    const float* __restrict__ log_dt, const float* __restrict__ Hr,
    const float* __restrict__ Hi, float2* __restrict__ ke) {
  const int q = blockIdx.x * 256 + threadIdx.x;  // 0..1279
  const int c = blockIdx.y;
  if (q > 1024) return;
  float s1r = 0.f, s1i = 0.f, s2r = 0.f, s2i = 0.f;
  if (q <= 1023) hope_sum(log_dt, Hr, Hi, c, q, &s1r, &s1i);        // k[c,q]
  if (q >= 1) hope_sum(log_dt, Hr, Hi, c + 512, q - 1, &s2r, &s2i); // k[c,2048-q]
  float kr, ki;
  if (q == 0)         { kr = s1r; ki = 0.f; }
  else if (q == 1024) { kr = s2r; ki = 0.f; }
  else                { kr = 0.5f * (s1r + s2r); ki = 0.5f * (s1i - s2i); }
  ke[c * 1026 + q] = make_float2(kr, ki);
}

// ---------------- radix-4 Stockham, 1024 pts, 256 threads, padded LDS ----------------
static __device__ __forceinline__ float2* fft1024(float2* S, float2* D, int tid,
                                                  const float2* __restrict__ tw) {
  #pragma unroll
  for (int t = 0; t < 5; ++t) {
    const int sh = 2 * t;
    const int m = 1 << sh;
    const int kk = tid & (m - 1);
    const int o = kk + ((tid >> sh) << (sh + 2));
    const float2 a = S[PHYS(tid)];
    const float2 b = S[PHYS(tid + 256)];
    const float2 c = S[PHYS(tid + 512)];
    const float2 d = S[PHYS(tid + 768)];
    const float apcr = a.x + c.x, apci = a.y + c.y;
    const float amcr = a.x - c.x, amci = a.y - c.y;
    const float bpdr = b.x + d.x, bpdi = b.y + d.y;
    const float bmdr = b.x - d.x, bmdi = b.y - d.y;
    const float2 y0 = make_float2(apcr + bpdr, apci + bpdi);
    const float2 y2 = make_float2(apcr - bpdr, apci - bpdi);
    const float2 y1 = make_float2(amcr + bmdi, amci - bmdr);
    const float2 y3 = make_float2(amcr - bmdi, amci + bmdr);
    const float2 w1 = tw[tid - kk];
    const float2 w2 = cmul(w1, w1);
    const float2 w3 = cmul(w2, w1);
    D[PHYS(o)] = y0;
    D[PHYS(o + m)] = cmul(w1, y1);
    D[PHYS(o + 2 * m)] = cmul(w2, y2);
    D[PHYS(o + 3 * m)] = cmul(w3, y3);
    __syncthreads();
    float2* ts = S; S = D; D = ts;
  }
  return S;
}

// ---------------- K2: rfft-conv via 1024-pt packed FFT + D-skip + GELU -> bf16 y
__global__ __launch_bounds__(256) void fft_conv(
    const float* __restrict__ u, const float2* __restrict__ ke,
    const float* __restrict__ Dv, u16* __restrict__ y) {
  __shared__ float2 bufA[1088], bufB[1088], twl[256];
  const int b = blockIdx.x, c = blockIdx.y;
  const int tid = threadIdx.x;
  {
    float s, cc;
    sincosf(6.28318530717958647692f * (float)tid * (1.f / 1024.f), &s, &cc);
    twl[tid] = make_float2(cc, -s);
  }
  const float* __restrict__ urow = u + ((size_t)(b * 512 + c)) * 2048;
  float ur[8];
  {
    const float4 v0 = ((const float4*)urow)[tid * 2];
    const float4 v1 = ((const float4*)urow)[tid * 2 + 1];
    ur[0] = v0.x; ur[1] = v0.y; ur[2] = v0.z; ur[3] = v0.w;
    ur[4] = v1.x; ur[5] = v1.y; ur[6] = v1.z; ur[7] = v1.w;
  }
  #pragma unroll
  for (int j = 0; j < 4; ++j)
    bufA[PHYS(4 * tid + j)] = make_float2(ur[2 * j], ur[2 * j + 1]);
  __syncthreads();

  float2* Z = fft1024(bufA, bufB, tid, twl);
  float2* D = (Z == bufA) ? bufB : bufA;

  const float2* __restrict__ kerow = ke + c * 1026;
  #pragma unroll
  for (int j = 0; j < 2; ++j) {
    const int f = tid + 256 * j;
    if (f == 0) {
      const float2 Z0 = Z[PHYS(0)];
      const float2 ke0 = kerow[0], keN = kerow[1024];
      const float X0 = Z0.x + Z0.y;
      const float XN = Z0.x - Z0.y;
      const float2 Y0 = make_float2(X0 * ke0.x, X0 * ke0.y);
      const float2 YN = make_float2(XN * keN.x, XN * keN.y);
      const float Pr = Y0.x + YN.x, Pi = Y0.y - YN.y;
      const float Qr = Y0.x - YN.x, Qi = Y0.y + YN.y;
      D[PHYS(0)] = make_float2(Pr - Qi, -(Pi + Qr));
      const float2 Z5 = Z[PHYS(512)];
      const float2 X5 = make_float2(Z5.x, -Z5.y);
      const float2 Y5 = cmul(X5, kerow[512]);
      D[PHYS(512)] = make_float2(2.f * Y5.x, 2.f * Y5.y);
    } else {
      const int g = 1024 - f;
      const float2 Zf = Z[PHYS(f)], Zg = Z[PHYS(g)];
      float st, ct;
      __sincosf(3.14159265358979323846f * (1.f / 1024.f) * (float)f, &st, &ct);
      const float Ar = 0.5f * (Zf.x + Zg.x), Ai = 0.5f * (Zf.y - Zg.y);
      const float Br = 0.5f * (Zf.x - Zg.x), Bi = 0.5f * (Zf.y + Zg.y);
      const float Cr = ct * Bi - st * Br, Ci = -(ct * Br + st * Bi);
      const float2 Xf = make_float2(Ar + Cr, Ai + Ci);
      const float2 Xg = make_float2(Ar - Cr, Ci - Ai);
      const float2 Yf = cmul(Xf, kerow[f]);
      const float2 Yg = cmul(Xg, kerow[g]);
      const float Pr = Yf.x + Yg.x, Pi = Yf.y - Yg.y;
      const float Qr = Yf.x - Yg.x, Qi = Yf.y + Yg.y;
      const float Rr = -(ct * Qi + st * Qr), Ri = ct * Qr - st * Qi;
      D[PHYS(f)] = make_float2(Pr + Rr, -(Pi + Ri));
      D[PHYS(g)] = make_float2(Pr - Rr, -(Ri - Pi));
    }
  }
  __syncthreads();

  float2* R = fft1024(D, Z, tid, twl);

  const float Dc = Dv[c];
  u16 ov[8];
  #pragma unroll
  for (int j = 0; j < 4; ++j) {
    const float2 r = R[PHYS(4 * tid + j)];
    const float ye = r.x * (1.f / 2048.f) + ur[2 * j] * Dc;
    const float yo = -r.y * (1.f / 2048.f) + ur[2 * j + 1] * Dc;
    const float ge = 0.5f * ye * (1.f + erff(ye * 0.70710678118654752440f));
    const float go = 0.5f * yo * (1.f + erff(yo * 0.70710678118654752440f));
    ov[2 * j] = f2bf(ge);
    ov[2 * j + 1] = f2bf(go);
  }
  *(u16x8*)(y + ((size_t)(b * 512 + c)) * 2048 + tid * 8) = *(u16x8*)ov;
}

// ---------------- K2b: y (B,C,L) bf16 -> yt (B,L,C) bf16 ----------------
__global__ __launch_bounds__(256) void transpose_y(
    const u16* __restrict__ y, u16* __restrict__ yt) {
  __shared__ u16 tile[64][80];
  const int b = blockIdx.z;
  const int tb = blockIdx.x * 64;
  const int cb = blockIdx.y * 64;
  const int tid = threadIdx.x;
  {
    const int tl = (tid & 7) * 8;
    const int cl = tid >> 3;
    #pragma unroll
    for (int h = 0; h < 2; ++h) {
      const int cc = cl + h * 32;
      const u16x8 v = *(const u16x8*)(y + ((size_t)(b * 512 + cb + cc)) * 2048 + tb + tl);
      #pragma unroll
      for (int i = 0; i < 8; ++i) tile[cc][tl + i] = v[i];
    }
  }
  __syncthreads();
  {
    const int c2 = (tid & 7) * 8;
    const int t2 = tid >> 3;
    #pragma unroll
    for (int h = 0; h < 2; ++h) {
      const int tt = t2 + h * 32;
      u16 tmp[8];
      #pragma unroll
      for (int i = 0; i < 8; ++i) tmp[i] = tile[c2 + i][tt];
      *(u16x8*)(yt + ((size_t)(b * 2048 + tb + tt)) * 512 + cb + c2) = *(u16x8*)tmp;
    }
  }
}

// ---------------- K2c: W f32 -> bf16 ----------------
__global__ __launch_bounds__(256) void conv_w(const float* __restrict__ W,
                                              u16* __restrict__ Wb) {
  const int i = blockIdx.x * 256 + threadIdx.x;
  Wb[i] = f2bf(W[i]);
}

// ---------------- K3: z = W*y + b, out = a * sigmoid(g) ----------------
// m97-structure: 128x128 tile, BK=64, global_load_lds(16B) staging, linear LDS.
// A-stack interleaves a/g rows: stack row sr -> W row (sr&1 ? 512+sr/2 : sr/2),
// so GLU pairing is intra-lane (C/D regs 0/1 and 2/3 are adjacent rows).
__global__ __launch_bounds__(256) void gemm_glu(
    const u16* __restrict__ Wb, const u16* __restrict__ yt,
    const float* __restrict__ bias, float* __restrict__ out) {
  __shared__ __align__(16) u16 Alds[128 * 64];  // [stack row r][k], linear
  __shared__ __align__(16) u16 Blds[128 * 64];  // [t row][k], linear
  const int b = blockIdx.z;
  const int m0 = blockIdx.y * 128;  // stack-row base (= 64 channels)
  const int t0 = blockIdx.x * 128;
  const int tid = threadIdx.x;
  const int lane = tid & 63, wid = tid >> 6;
  const int wm = wid >> 1, wn = wid & 1;        // 2x2 waves, 64x64 each
  const int lrow = lane & 15, lk8 = (lane >> 4) * 8;

  // staging decomposition: issue q covers rows q*32..q*32+31; each lane loads
  // 16B at (row = q*32 + tid>>3, k-elem = kk + (tid&7)*8); LDS dest is
  // wave-uniform base + lane*16 which equals row*128 + kelem*2 bytes exactly.
  const int rst = tid >> 3;         // 0..31
  const int kst = (tid & 7) * 8;
  const int wofs = (tid >> 6) * 1024;

  f32x4 acc[4][4];
  const f32x4 z4 = {0.f, 0.f, 0.f, 0.f};
  #pragma unroll
  for (int mi = 0; mi < 4; ++mi)
    #pragma unroll
    for (int ni = 0; ni < 4; ++ni) acc[mi][ni] = z4;

  for (int kk = 0; kk < 512; kk += 64) {
    if (kk) __syncthreads();        // all waves done reading LDS of prev step
    #pragma unroll
    for (int q = 0; q < 4; ++q) {
      const int r = q * 32 + rst;
      const int sr = m0 + r;
      const int o = (sr & 1) ? (512 + (sr >> 1)) : (sr >> 1);
      gload_lds16(Wb + (size_t)o * 512 + kk + kst,
                  (char*)Alds + q * 4096 + wofs);
      gload_lds16(yt + ((size_t)(b * 2048 + t0 + r)) * 512 + kk + kst,
                  (char*)Blds + q * 4096 + wofs);
    }
    __syncthreads();                // drains vmcnt(0): staged data visible
    #pragma unroll
    for (int s = 0; s < 2; ++s) {   // two k-slices of 32 within BK=64
      short8 af[4], bf[4];
      #pragma unroll
      for (int mi = 0; mi < 4; ++mi)
        af[mi] = __builtin_bit_cast(short8,
                 *(const u16x8*)&Alds[(wm * 64 + mi * 16 + lrow) * 64 + s * 32 + lk8]);
      #pragma unroll
      for (int ni = 0; ni < 4; ++ni)
        bf[ni] = __builtin_bit_cast(short8,
                 *(const u16x8*)&Blds[(wn * 64 + ni * 16 + lrow) * 64 + s * 32 + lk8]);
      #pragma unroll
      for (int mi = 0; mi < 4; ++mi)
        #pragma unroll
        for (int ni = 0; ni < 4; ++ni)
          acc[mi][ni] = __builtin_amdgcn_mfma_f32_16x16x32_bf16(af[mi], bf[ni],
                                                                acc[mi][ni], 0, 0, 0);
    }
  }

  const int rsub = (lane >> 4) * 4;  // C/D: row = (lane>>4)*4 + reg, col = lane&15
  #pragma unroll
  for (int mi = 0; mi < 4; ++mi) {
    const int rb = wm * 64 + mi * 16 + rsub;   // even
    const int ch = (m0 + rb) >> 1;
    const float ba0 = bias[ch],     bg0 = bias[512 + ch];
    const float ba1 = bias[ch + 1], bg1 = bias[512 + ch + 1];
    #pragma unroll
    for (int ni = 0; ni < 4; ++ni) {
      const int t = t0 + wn * 64 + ni * 16 + (lane & 15);
      const f32x4 v = acc[mi][ni];
      const float a0 = v[0] + ba0, g0 = v[1] + bg0;
      const float a1 = v[2] + ba1, g1 = v[3] + bg1;
      out[((size_t)(b * 512 + ch)) * 2048 + t]     = a0 / (1.f + expf(-g0));
      out[((size_t)(b * 512 + ch + 1)) * 2048 + t] = a1 / (1.f + expf(-g1));
    }
  }
}

extern "C" void kernel_launch(void* const* d_in, const int* in_sizes, int n_in,
                              void* d_out, int out_size, void* d_ws, size_t ws_size,
                              hipStream_t stream) {
  (void)in_sizes; (void)n_in; (void)out_size; (void)ws_size;
  const float* u      = (const float*)d_in[0];
  const float* log_dt = (const float*)d_in[1];
  const float* Hr     = (const float*)d_in[2];
  const float* Hi     = (const float*)d_in[3];
  const float* Dv     = (const float*)d_in[4];
  const float* W      = (const float*)d_in[5];
  const float* bias   = (const float*)d_in[6];

  char* ws = (char*)d_ws;
  float2* ke = (float2*)(ws);                      // 512*1026*8 = 4.2 MB
  u16*    Wb = (u16*)  (ws + ((size_t)5 << 20));   // 1 MB
  u16*    yt = (u16*)  (ws + ((size_t)8 << 20));   // 32 MB
  u16*    ybf = (u16*)d_out;                       // bf16 y staged in d_out

  build_ke<<<dim3(5, 512), 256, 0, stream>>>(log_dt, Hr, Hi, ke);
  conv_w<<<dim3(2048), 256, 0, stream>>>(W, Wb);
  fft_conv<<<dim3(16, 512), 256, 0, stream>>>(u, ke, Dv, ybf);
  transpose_y<<<dim3(32, 8, 16), 256, 0, stream>>>(ybf, yt);
  gemm_glu<<<dim3(16, 8, 16), 256, 0, stream>>>(Wb, yt, bias, (float*)d_out);
}

// Round 4
// 143.693 us; speedup vs baseline: 1.9978x; 1.0703x over previous
//
#include <hip/hip_runtime.h>
#include <math.h>

typedef unsigned short u16;
typedef unsigned int u32;
typedef __attribute__((ext_vector_type(8))) short short8;
typedef __attribute__((ext_vector_type(8))) u16 u16x8;
typedef __attribute__((ext_vector_type(4))) float f32x4;

#define PHYS(i) ((i) + ((i) >> 4))

static __device__ __forceinline__ u16 f2bf(float x) {
  unsigned u = __builtin_bit_cast(unsigned, x);
  return (u16)((u + 0x7FFFu + ((u >> 16) & 1u)) >> 16);
}

static __device__ __forceinline__ float2 cmul(float2 a, float2 b) {
  return make_float2(a.x * b.x - a.y * b.y, a.x * b.y + a.y * b.x);
}

// async global->LDS, 16B per lane; dest = wave-uniform base + lane*16
static __device__ __forceinline__ void gload_lds16(const void* g, void* l) {
  __builtin_amdgcn_global_load_lds(
      (const __attribute__((address_space(1))) u32*)g,
      (__attribute__((address_space(3))) u32*)l, 16, 0, 0);
}

// ---------------- K1: ke[c,q] = (k[c,q] + conj(k[c,(2048-q)%2048]))/2, q=0..1024
static __device__ __forceinline__ void hope_sum(
    const float* __restrict__ log_dt, const float* __restrict__ Hr,
    const float* __restrict__ Hi, int h, int l, float* outr, float* outi) {
  const float dt = expf(log_dt[h]);
  const float phi = 6.28318530717958647692f * (float)l * (1.0f / 1024.0f);
  float sphi, cphi;
  sincosf(phi, &sphi, &cphi);
  const float nr = (1.f + dt) * cphi + dt - 1.f;
  const float ni = (1.f + dt) * sphi;
  const float dr = (dt - 1.f) * cphi + dt + 1.f;
  const float di = (dt - 1.f) * sphi;
  const float theta = atan2f(ni * dr - nr * di, nr * dr + ni * di);
  float sw, cw;
  sincosf(theta, &sw, &cw);
  const float wr = cw, wi = -sw;  // e^{-i theta}
  float cr = wr, ci = wi;
  float ar = 0.f, ai = 0.f;
  const float* __restrict__ hr = Hr + h * 64;
  const float* __restrict__ hi = Hi + h * 64;
  for (int n = 0; n < 64; ++n) {
    const float a = hr[n], bb = hi[n];
    ar += a * cr - bb * ci;
    ai += a * ci + bb * cr;
    const float t = cr * wr - ci * wi;
    ci = cr * wi + ci * wr;
    cr = t;
  }
  *outr = ar;
  *outi = ai;
}

__global__ __launch_bounds__(256) void build_ke(
    const float* __restrict__ log_dt, const float* __restrict__ Hr,
    const float* __restrict__ Hi, float2* __restrict__ ke) {
  const int q = blockIdx.x * 256 + threadIdx.x;  // 0..1279
  const int c = blockIdx.y;
  if (q > 1024) return;
  float s1r = 0.f, s1i = 0.f, s2r = 0.f, s2i = 0.f;
  if (q <= 1023) hope_sum(log_dt, Hr, Hi, c, q, &s1r, &s1i);        // k[c,q]
  if (q >= 1) hope_sum(log_dt, Hr, Hi, c + 512, q - 1, &s2r, &s2i); // k[c,2048-q]
  float kr, ki;
  if (q == 0)         { kr = s1r; ki = 0.f; }
  else if (q == 1024) { kr = s2r; ki = 0.f; }
  else                { kr = 0.5f * (s1r + s2r); ki = 0.5f * (s1i - s2i); }
  ke[c * 1026 + q] = make_float2(kr, ki);
}

// ---------------- radix-4 Stockham, 1024 pts, 256 threads, padded LDS ----------------
static __device__ __forceinline__ float2* fft1024(float2* S, float2* D, int tid,
                                                  const float2* __restrict__ tw) {
  #pragma unroll
  for (int t = 0; t < 5; ++t) {
    const int sh = 2 * t;
    const int m = 1 << sh;
    const int kk = tid & (m - 1);
    const int o = kk + ((tid >> sh) << (sh + 2));
    const float2 a = S[PHYS(tid)];
    const float2 b = S[PHYS(tid + 256)];
    const float2 c = S[PHYS(tid + 512)];
    const float2 d = S[PHYS(tid + 768)];
    const float apcr = a.x + c.x, apci = a.y + c.y;
    const float amcr = a.x - c.x, amci = a.y - c.y;
    const float bpdr = b.x + d.x, bpdi = b.y + d.y;
    const float bmdr = b.x - d.x, bmdi = b.y - d.y;
    const float2 y0 = make_float2(apcr + bpdr, apci + bpdi);
    const float2 y2 = make_float2(apcr - bpdr, apci - bpdi);
    const float2 y1 = make_float2(amcr + bmdi, amci - bmdr);
    const float2 y3 = make_float2(amcr - bmdi, amci + bmdr);
    const float2 w1 = tw[tid - kk];
    const float2 w2 = cmul(w1, w1);
    const float2 w3 = cmul(w2, w1);
    D[PHYS(o)] = y0;
    D[PHYS(o + m)] = cmul(w1, y1);
    D[PHYS(o + 2 * m)] = cmul(w2, y2);
    D[PHYS(o + 3 * m)] = cmul(w3, y3);
    __syncthreads();
    float2* ts = S; S = D; D = ts;
  }
  return S;
}

// ---------------- K2: rfft-conv via 1024-pt packed FFT + D-skip + GELU -> bf16 y
__global__ __launch_bounds__(256) void fft_conv(
    const float* __restrict__ u, const float2* __restrict__ ke,
    const float* __restrict__ Dv, u16* __restrict__ y) {
  __shared__ float2 bufA[1088], bufB[1088], twl[256];
  const int b = blockIdx.x, c = blockIdx.y;
  const int tid = threadIdx.x;
  {
    float s, cc;
    sincosf(6.28318530717958647692f * (float)tid * (1.f / 1024.f), &s, &cc);
    twl[tid] = make_float2(cc, -s);
  }
  const float* __restrict__ urow = u + ((size_t)(b * 512 + c)) * 2048;
  float ur[8];
  {
    const float4 v0 = ((const float4*)urow)[tid * 2];
    const float4 v1 = ((const float4*)urow)[tid * 2 + 1];
    ur[0] = v0.x; ur[1] = v0.y; ur[2] = v0.z; ur[3] = v0.w;
    ur[4] = v1.x; ur[5] = v1.y; ur[6] = v1.z; ur[7] = v1.w;
  }
  #pragma unroll
  for (int j = 0; j < 4; ++j)
    bufA[PHYS(4 * tid + j)] = make_float2(ur[2 * j], ur[2 * j + 1]);
  __syncthreads();

  float2* Z = fft1024(bufA, bufB, tid, twl);
  float2* D = (Z == bufA) ? bufB : bufA;

  const float2* __restrict__ kerow = ke + c * 1026;
  #pragma unroll
  for (int j = 0; j < 2; ++j) {
    const int f = tid + 256 * j;
    if (f == 0) {
      const float2 Z0 = Z[PHYS(0)];
      const float2 ke0 = kerow[0], keN = kerow[1024];
      const float X0 = Z0.x + Z0.y;
      const float XN = Z0.x - Z0.y;
      const float2 Y0 = make_float2(X0 * ke0.x, X0 * ke0.y);
      const float2 YN = make_float2(XN * keN.x, XN * keN.y);
      const float Pr = Y0.x + YN.x, Pi = Y0.y - YN.y;
      const float Qr = Y0.x - YN.x, Qi = Y0.y + YN.y;
      D[PHYS(0)] = make_float2(Pr - Qi, -(Pi + Qr));
      const float2 Z5 = Z[PHYS(512)];
      const float2 X5 = make_float2(Z5.x, -Z5.y);
      const float2 Y5 = cmul(X5, kerow[512]);
      D[PHYS(512)] = make_float2(2.f * Y5.x, 2.f * Y5.y);
    } else {
      const int g = 1024 - f;
      const float2 Zf = Z[PHYS(f)], Zg = Z[PHYS(g)];
      float st, ct;
      __sincosf(3.14159265358979323846f * (1.f / 1024.f) * (float)f, &st, &ct);
      const float Ar = 0.5f * (Zf.x + Zg.x), Ai = 0.5f * (Zf.y - Zg.y);
      const float Br = 0.5f * (Zf.x - Zg.x), Bi = 0.5f * (Zf.y + Zg.y);
      const float Cr = ct * Bi - st * Br, Ci = -(ct * Br + st * Bi);
      const float2 Xf = make_float2(Ar + Cr, Ai + Ci);
      const float2 Xg = make_float2(Ar - Cr, Ci - Ai);
      const float2 Yf = cmul(Xf, kerow[f]);
      const float2 Yg = cmul(Xg, kerow[g]);
      const float Pr = Yf.x + Yg.x, Pi = Yf.y - Yg.y;
      const float Qr = Yf.x - Yg.x, Qi = Yf.y + Yg.y;
      const float Rr = -(ct * Qi + st * Qr), Ri = ct * Qr - st * Qi;
      D[PHYS(f)] = make_float2(Pr + Rr, -(Pi + Ri));
      D[PHYS(g)] = make_float2(Pr - Rr, -(Ri - Pi));
    }
  }
  __syncthreads();

  float2* R = fft1024(D, Z, tid, twl);

  const float Dc = Dv[c];
  u16 ov[8];
  #pragma unroll
  for (int j = 0; j < 4; ++j) {
    const float2 r = R[PHYS(4 * tid + j)];
    const float ye = r.x * (1.f / 2048.f) + ur[2 * j] * Dc;
    const float yo = -r.y * (1.f / 2048.f) + ur[2 * j + 1] * Dc;
    const float ge = 0.5f * ye * (1.f + erff(ye * 0.70710678118654752440f));
    const float go = 0.5f * yo * (1.f + erff(yo * 0.70710678118654752440f));
    ov[2 * j] = f2bf(ge);
    ov[2 * j + 1] = f2bf(go);
  }
  *(u16x8*)(y + ((size_t)(b * 512 + c)) * 2048 + tid * 8) = *(u16x8*)ov;
}

// ---------------- K2b: y (B,C,L) bf16 -> yt (B,L,C) bf16 ----------------
__global__ __launch_bounds__(256) void transpose_y(
    const u16* __restrict__ y, u16* __restrict__ yt) {
  __shared__ u16 tile[64][80];
  const int b = blockIdx.z;
  const int tb = blockIdx.x * 64;
  const int cb = blockIdx.y * 64;
  const int tid = threadIdx.x;
  {
    const int tl = (tid & 7) * 8;
    const int cl = tid >> 3;
    #pragma unroll
    for (int h = 0; h < 2; ++h) {
      const int cc = cl + h * 32;
      const u16x8 v = *(const u16x8*)(y + ((size_t)(b * 512 + cb + cc)) * 2048 + tb + tl);
      #pragma unroll
      for (int i = 0; i < 8; ++i) tile[cc][tl + i] = v[i];
    }
  }
  __syncthreads();
  {
    const int c2 = (tid & 7) * 8;
    const int t2 = tid >> 3;
    #pragma unroll
    for (int h = 0; h < 2; ++h) {
      const int tt = t2 + h * 32;
      u16 tmp[8];
      #pragma unroll
      for (int i = 0; i < 8; ++i) tmp[i] = tile[c2 + i][tt];
      *(u16x8*)(yt + ((size_t)(b * 2048 + tb + tt)) * 512 + cb + c2) = *(u16x8*)tmp;
    }
  }
}

// ---------------- K2c: W f32 -> bf16 ----------------
__global__ __launch_bounds__(256) void conv_w(const float* __restrict__ W,
                                              u16* __restrict__ Wb) {
  const int i = blockIdx.x * 256 + threadIdx.x;
  Wb[i] = f2bf(W[i]);
}

// ---------------- K3: 256x256x(K=512) 8-phase GEMM + GLU ----------------
// A = interleaved W stack (a/g rows), B = yt. 8 waves (2M x 4N), per-wave 128x64.
// LDS 128KB: A[2buf][2half][128][64], B likewise at +32768 u16.
// Swizzle: 16B-slot ^= (row&7), applied on global source col AND ds_read col.
#define FRAG_A(P, MI, S) __builtin_bit_cast(short8, *(const u16x8*)&lds[       \
    (P) * 16384 + wmh + ((MI) * 16 + lrow) * 64 + ((S) ? cs1 : cs0)])
#define FRAG_B(P, NI, S) __builtin_bit_cast(short8, *(const u16x8*)&lds[       \
    32768 + (P) * 16384 + hBh + (rB + (NI) * 16 + lrow) * 64 + ((S) ? cs1 : cs0)])

#define STAGE_A(KT, H, P) do {                                                 \
    int sr_ = m0 + (H) * 128 + wq8 + l3;                                       \
    int o0_ = (sr_ & 1) ? (512 + (sr_ >> 1)) : (sr_ >> 1);                     \
    gload_lds16(Wb + (size_t)o0_ * 512 + (KT) * 64 + csw,                      \
                lds + (P) * 16384 + (H) * 8192 + wq * 512);                    \
    sr_ += 64;                                                                 \
    int o1_ = (sr_ & 1) ? (512 + (sr_ >> 1)) : (sr_ >> 1);                     \
    gload_lds16(Wb + (size_t)o1_ * 512 + (KT) * 64 + csw,                      \
                lds + (P) * 16384 + (H) * 8192 + 4096 + wq * 512);             \
  } while (0)
#define STAGE_B(KT, H, P) do {                                                 \
    int tr_ = t0b + (H) * 128 + wq8 + l3;                                      \
    gload_lds16(yt + ((size_t)(bb * 2048 + tr_)) * 512 + (KT) * 64 + csw,      \
                lds + 32768 + (P) * 16384 + (H) * 8192 + wq * 512);            \
    gload_lds16(yt + ((size_t)(bb * 2048 + tr_ + 64)) * 512 + (KT) * 64 + csw, \
                lds + 32768 + (P) * 16384 + (H) * 8192 + 4096 + wq * 512);     \
  } while (0)

#define MFMA2(MI, NI, A0, A1)                                                  \
    acc[MI][NI] = __builtin_amdgcn_mfma_f32_16x16x32_bf16(A0, br[NI][0],       \
                                                          acc[MI][NI], 0, 0, 0); \
    acc[MI][NI] = __builtin_amdgcn_mfma_f32_16x16x32_bf16(A1, br[NI][1],       \
                                                          acc[MI][NI], 0, 0, 0);

#define PHASE_CORE(Q, READS, STAGES, VWAIT)                                    \
  {                                                                            \
    short8 a00 = FRAG_A(PP, (Q)*2 + 0, 0), a01 = FRAG_A(PP, (Q)*2 + 0, 1);     \
    short8 a10 = FRAG_A(PP, (Q)*2 + 1, 0), a11 = FRAG_A(PP, (Q)*2 + 1, 1);     \
    READS;                                                                     \
    STAGES;                                                                    \
    __builtin_amdgcn_s_barrier();                                              \
    asm volatile("s_waitcnt lgkmcnt(0)" ::: "memory");                         \
    __builtin_amdgcn_sched_barrier(0);                                         \
    __builtin_amdgcn_s_setprio(1);                                             \
    MFMA2((Q)*2 + 0, 0, a00, a01) MFMA2((Q)*2 + 0, 1, a00, a01)                \
    MFMA2((Q)*2 + 0, 2, a00, a01) MFMA2((Q)*2 + 0, 3, a00, a01)                \
    MFMA2((Q)*2 + 1, 0, a10, a11) MFMA2((Q)*2 + 1, 1, a10, a11)                \
    MFMA2((Q)*2 + 1, 2, a10, a11) MFMA2((Q)*2 + 1, 3, a10, a11)                \
    __builtin_amdgcn_s_setprio(0);                                             \
    __builtin_amdgcn_sched_barrier(0);                                         \
    VWAIT;                                                                     \
    __builtin_amdgcn_s_barrier();                                              \
  }

#define READ_B(P) do {                                                         \
    br[0][0] = FRAG_B(P, 0, 0); br[0][1] = FRAG_B(P, 0, 1);                    \
    br[1][0] = FRAG_B(P, 1, 0); br[1][1] = FRAG_B(P, 1, 1);                    \
    br[2][0] = FRAG_B(P, 2, 0); br[2][1] = FRAG_B(P, 2, 1);                    \
    br[3][0] = FRAG_B(P, 3, 0); br[3][1] = FRAG_B(P, 3, 1);                    \
  } while (0)

__global__ __launch_bounds__(512, 2) void gemm_glu(
    const u16* __restrict__ Wb, const u16* __restrict__ yt,
    const float* __restrict__ bias, float* __restrict__ out) {
  extern __shared__ __align__(16) u16 lds[];
  const int bid = blockIdx.x;
  const int wg = (bid & 7) * 64 + (bid >> 3);  // XCD swizzle (512 = 8*64)
  const int bb = wg >> 5;                      // batch
  const int mt = (wg >> 3) & 3;
  const int nt = wg & 7;
  const int m0 = mt * 256;
  const int t0b = nt * 256;
  const int tid = threadIdx.x;
  const int lane = tid & 63;
  const int wq = tid >> 6;                     // wave 0..7
  const int wq8 = wq * 8, l3 = lane >> 3;
  const int wm = wq >> 2, wn = wq & 3;
  const int lrow = lane & 15, lq = lane >> 4;
  const int csw = ((lane & 7) ^ l3) * 8;       // pre-swizzled global col
  const int cs0 = ((lq ^ (lane & 7)) << 3);
  const int cs1 = (((4 + lq) ^ (lane & 7)) << 3);
  const int wmh = wm * 8192;                   // A half base (u16)
  const int hBh = (wn >> 1) * 8192;            // B half base (u16)
  const int rB = (wn & 1) * 64;

  f32x4 acc[8][4];
  const f32x4 z4 = {0.f, 0.f, 0.f, 0.f};
  #pragma unroll
  for (int mi = 0; mi < 8; ++mi)
    #pragma unroll
    for (int ni = 0; ni < 4; ++ni) acc[mi][ni] = z4;
  short8 br[4][2];

  // prologue: tile0 (A+B -> buf0), tile1 B -> buf1
  STAGE_A(0, 0, 0); STAGE_A(0, 1, 0);
  STAGE_B(0, 0, 0); STAGE_B(0, 1, 0);
  STAGE_B(1, 0, 1); STAGE_B(1, 1, 1);
  asm volatile("s_waitcnt vmcnt(4)" ::: "memory");  // tile0's 8 loads landed
  __builtin_amdgcn_s_barrier();

  #pragma unroll
  for (int j = 0; j < 4; ++j) {
    const int e2 = 2 * j + 2, o1 = 2 * j + 1, o3 = 2 * j + 3;
    // even tile (buf0)
    #define PP 0
    PHASE_CORE(0, READ_B(0), STAGE_A(o1, 0, 1), )
    PHASE_CORE(1, , { STAGE_A(o1, 1, 1); if (j < 3) STAGE_B(e2, 0, 0); }, )
    PHASE_CORE(2, , if (j < 3) STAGE_B(e2, 1, 0), )
    PHASE_CORE(3, , ,
               if (j < 3) { asm volatile("s_waitcnt vmcnt(4)" ::: "memory"); }
               else { asm volatile("s_waitcnt vmcnt(0)" ::: "memory"); })
    #undef PP
    // odd tile (buf1)
    #define PP 1
    PHASE_CORE(0, READ_B(1), if (j < 3) STAGE_A(e2, 0, 0), )
    PHASE_CORE(1, , if (j < 3) STAGE_A(e2, 1, 0), )
    PHASE_CORE(2, , if (j < 3) STAGE_B(o3, 0, 1), )
    PHASE_CORE(3, , if (j < 3) STAGE_B(o3, 1, 1),
               if (j < 3) { asm volatile("s_waitcnt vmcnt(4)" ::: "memory"); })
    #undef PP
  }

  #pragma unroll
  for (int mi = 0; mi < 8; ++mi) {
    const int sr0 = m0 + wm * 128 + mi * 16 + lq * 4;  // even stack row
    const int ch = sr0 >> 1;
    const float ba0 = bias[ch],     bg0 = bias[512 + ch];
    const float ba1 = bias[ch + 1], bg1 = bias[512 + ch + 1];
    #pragma unroll
    for (int ni = 0; ni < 4; ++ni) {
      const int t = t0b + wn * 64 + ni * 16 + (lane & 15);
      const f32x4 v = acc[mi][ni];
      const float a0 = v[0] + ba0, g0 = v[1] + bg0;
      const float a1 = v[2] + ba1, g1 = v[3] + bg1;
      out[((size_t)(bb * 512 + ch)) * 2048 + t]     = a0 / (1.f + expf(-g0));
      out[((size_t)(bb * 512 + ch + 1)) * 2048 + t] = a1 / (1.f + expf(-g1));
    }
  }
}

extern "C" void kernel_launch(void* const* d_in, const int* in_sizes, int n_in,
                              void* d_out, int out_size, void* d_ws, size_t ws_size,
                              hipStream_t stream) {
  (void)in_sizes; (void)n_in; (void)out_size; (void)ws_size;
  const float* u      = (const float*)d_in[0];
  const float* log_dt = (const float*)d_in[1];
  const float* Hr     = (const float*)d_in[2];
  const float* Hi     = (const float*)d_in[3];
  const float* Dv     = (const float*)d_in[4];
  const float* W      = (const float*)d_in[5];
  const float* bias   = (const float*)d_in[6];

  char* ws = (char*)d_ws;
  float2* ke = (float2*)(ws);                      // 4.2 MB
  u16*    Wb = (u16*)  (ws + ((size_t)5 << 20));   // 1 MB
  u16*    yt = (u16*)  (ws + ((size_t)8 << 20));   // 32 MB
  u16*    ybf = (u16*)d_out;                       // bf16 y staged in d_out

  build_ke<<<dim3(5, 512), 256, 0, stream>>>(log_dt, Hr, Hi, ke);
  conv_w<<<dim3(2048), 256, 0, stream>>>(W, Wb);
  fft_conv<<<dim3(16, 512), 256, 0, stream>>>(u, ke, Dv, ybf);
  transpose_y<<<dim3(32, 8, 16), 256, 0, stream>>>(ybf, yt);
  gemm_glu<<<dim3(512), 512, 131072, stream>>>(Wb, yt, bias, (float*)d_out);
}

// Round 5
// 134.297 us; speedup vs baseline: 2.1376x; 1.0700x over previous
//
#include <hip/hip_runtime.h>
#include <math.h>

typedef unsigned short u16;
typedef unsigned int u32;
typedef __attribute__((ext_vector_type(8))) short short8;
typedef __attribute__((ext_vector_type(8))) u16 u16x8;
typedef __attribute__((ext_vector_type(4))) float f32x4;

#define PHYS(i) ((i) + ((i) >> 4))

#if __has_builtin(__builtin_amdgcn_rcpf)
#define RCP(x) __builtin_amdgcn_rcpf(x)
#else
#define RCP(x) (1.0f / (x))
#endif

static __device__ __forceinline__ u16 f2bf(float x) {
  unsigned u = __builtin_bit_cast(unsigned, x);
  return (u16)((u + 0x7FFFu + ((u >> 16) & 1u)) >> 16);
}

static __device__ __forceinline__ float2 cmul(float2 a, float2 b) {
  return make_float2(a.x * b.x - a.y * b.y, a.x * b.y + a.y * b.x);
}

// tanh-form GELU: y * sigmoid(1.59577*(y + 0.044715 y^3)); max dev ~1e-3
static __device__ __forceinline__ float gelu_fast(float y) {
  const float t = __builtin_fmaf(0.044715f * y * y, y, y);
  const float e = __expf(-1.5957691216f * t);
  return y * RCP(1.f + e);
}

// async global->LDS, 16B per lane; dest = wave-uniform base + lane*16
static __device__ __forceinline__ void gload_lds16(const void* g, void* l) {
  __builtin_amdgcn_global_load_lds(
      (const __attribute__((address_space(1))) u32*)g,
      (__attribute__((address_space(3))) u32*)l, 16, 0, 0);
}

// ---------------- K1: ke[c,q] = (k[c,q]+conj(k[c,(2048-q)%2048]))/2 /2048
static __device__ __forceinline__ void hope_sum(
    const float* __restrict__ log_dt, const float* __restrict__ Hr,
    const float* __restrict__ Hi, int h, int l, float* outr, float* outi) {
  const float dt = expf(log_dt[h]);
  const float phi = 6.28318530717958647692f * (float)l * (1.0f / 1024.0f);
  float sphi, cphi;
  sincosf(phi, &sphi, &cphi);
  const float nr = (1.f + dt) * cphi + dt - 1.f;
  const float ni = (1.f + dt) * sphi;
  const float dr = (dt - 1.f) * cphi + dt + 1.f;
  const float di = (dt - 1.f) * sphi;
  const float theta = atan2f(ni * dr - nr * di, nr * dr + ni * di);
  float sw, cw;
  sincosf(theta, &sw, &cw);
  const float wr = cw, wi = -sw;  // e^{-i theta}
  float cr = wr, ci = wi;
  float ar = 0.f, ai = 0.f;
  const float* __restrict__ hr = Hr + h * 64;
  const float* __restrict__ hi = Hi + h * 64;
  for (int n = 0; n < 64; ++n) {
    const float a = hr[n], bb = hi[n];
    ar += a * cr - bb * ci;
    ai += a * ci + bb * cr;
    const float t = cr * wr - ci * wi;
    ci = cr * wi + ci * wr;
    cr = t;
  }
  *outr = ar;
  *outi = ai;
}

__global__ __launch_bounds__(256) void build_ke(
    const float* __restrict__ log_dt, const float* __restrict__ Hr,
    const float* __restrict__ Hi, float2* __restrict__ ke) {
  const int q = blockIdx.x * 256 + threadIdx.x;  // 0..1279
  const int c = blockIdx.y;
  if (q > 1024) return;
  float s1r = 0.f, s1i = 0.f, s2r = 0.f, s2i = 0.f;
  if (q <= 1023) hope_sum(log_dt, Hr, Hi, c, q, &s1r, &s1i);        // k[c,q]
  if (q >= 1) hope_sum(log_dt, Hr, Hi, c + 512, q - 1, &s2r, &s2i); // k[c,2048-q]
  float kr, ki;
  if (q == 0)         { kr = s1r; ki = 0.f; }
  else if (q == 1024) { kr = s2r; ki = 0.f; }
  else                { kr = 0.5f * (s1r + s2r); ki = 0.5f * (s1i - s2i); }
  const float s = 1.0f / 2048.0f;  // fold ifft scale into ke (exact)
  ke[c * 1026 + q] = make_float2(kr * s, ki * s);
}

// ---------------- radix-4 Stockham stage, 1024 pts, 256 threads/row ----------------
static __device__ __forceinline__ void fft_stage(
    float2* __restrict__ S, float2* __restrict__ D, int tsub, int sh,
    const float2* __restrict__ tw) {
  const int m = 1 << sh;
  const int kk = tsub & (m - 1);
  const int o = kk + ((tsub >> sh) << (sh + 2));
  const float2 a = S[PHYS(tsub)];
  const float2 b = S[PHYS(tsub + 256)];
  const float2 c = S[PHYS(tsub + 512)];
  const float2 d = S[PHYS(tsub + 768)];
  const float apcr = a.x + c.x, apci = a.y + c.y;
  const float amcr = a.x - c.x, amci = a.y - c.y;
  const float bpdr = b.x + d.x, bpdi = b.y + d.y;
  const float bmdr = b.x - d.x, bmdi = b.y - d.y;
  const float2 y0 = make_float2(apcr + bpdr, apci + bpdi);
  const float2 y2 = make_float2(apcr - bpdr, apci - bpdi);
  const float2 y1 = make_float2(amcr + bmdi, amci - bmdr);
  const float2 y3 = make_float2(amcr - bmdi, amci + bmdr);
  D[PHYS(o)] = y0;
  if (sh == 8) {  // last stage: tsub-kk == 0 -> w1 = 1, skip twiddles
    D[PHYS(o + m)] = y1;
    D[PHYS(o + 2 * m)] = y2;
    D[PHYS(o + 3 * m)] = y3;
  } else {
    const float2 w1 = tw[tsub - kk];
    const float2 w2 = cmul(w1, w1);
    const float2 w3 = cmul(w2, w1);
    D[PHYS(o + m)] = cmul(w1, y1);
    D[PHYS(o + 2 * m)] = cmul(w2, y2);
    D[PHYS(o + 3 * m)] = cmul(w3, y3);
  }
}

// ---------------- K2: rfft-conv, 2 rows/block (b, b+8), 512 threads ----------------
__global__ __launch_bounds__(512) void fft_conv(
    const float* __restrict__ u, const float2* __restrict__ ke,
    const float* __restrict__ Dv, u16* __restrict__ y) {
  __shared__ float2 bufA[2176], bufB[2176];  // 2 rows x 1088
  __shared__ float2 twl[256];
  const int bq = blockIdx.x, c = blockIdx.y;
  const int tid = threadIdx.x;
  const int half = tid >> 8, tsub = tid & 255;
  const int b = bq + 8 * half;
  if (tid < 256) {
    float s, cc;
    __sincosf(6.28318530717958647692f * (float)tid * (1.f / 1024.f), &s, &cc);
    twl[tid] = make_float2(cc, -s);
  }
  const float* __restrict__ urow = u + ((size_t)(b * 512 + c)) * 2048;
  float ur[8];
  {
    const float4 v0 = ((const float4*)urow)[tsub * 2];
    const float4 v1 = ((const float4*)urow)[tsub * 2 + 1];
    ur[0] = v0.x; ur[1] = v0.y; ur[2] = v0.z; ur[3] = v0.w;
    ur[4] = v1.x; ur[5] = v1.y; ur[6] = v1.z; ur[7] = v1.w;
  }
  float2* S = bufA + half * 1088;
  float2* Dp = bufB + half * 1088;
  #pragma unroll
  for (int j = 0; j < 4; ++j)
    S[PHYS(4 * tsub + j)] = make_float2(ur[2 * j], ur[2 * j + 1]);
  __syncthreads();

  #pragma unroll
  for (int t = 0; t < 5; ++t) {  // forward FFT of packed z
    fft_stage(S, Dp, tsub, 2 * t, twl);
    __syncthreads();
    float2* tp = S; S = Dp; Dp = tp;
  }

  // pointwise: unpack rfft bins, * ke (pre-scaled by 1/2048), repack conj
  const float2* __restrict__ kerow = ke + c * 1026;
  #pragma unroll
  for (int j = 0; j < 2; ++j) {
    const int f = tsub + 256 * j;
    if (f == 0) {
      const float2 Z0 = S[PHYS(0)];
      const float2 ke0 = kerow[0], keN = kerow[1024];
      const float X0 = Z0.x + Z0.y;
      const float XN = Z0.x - Z0.y;
      const float2 Y0 = make_float2(X0 * ke0.x, X0 * ke0.y);
      const float2 YN = make_float2(XN * keN.x, XN * keN.y);
      const float Pr = Y0.x + YN.x, Pi = Y0.y - YN.y;
      const float Qr = Y0.x - YN.x, Qi = Y0.y + YN.y;
      Dp[PHYS(0)] = make_float2(Pr - Qi, -(Pi + Qr));
      const float2 Z5 = S[PHYS(512)];
      const float2 X5 = make_float2(Z5.x, -Z5.y);
      const float2 Y5 = cmul(X5, kerow[512]);
      Dp[PHYS(512)] = make_float2(2.f * Y5.x, 2.f * Y5.y);
    } else {
      const int g = 1024 - f;
      const float2 Zf = S[PHYS(f)], Zg = S[PHYS(g)];
      float st, ct;
      __sincosf(3.14159265358979323846f * (1.f / 1024.f) * (float)f, &st, &ct);
      const float Ar = 0.5f * (Zf.x + Zg.x), Ai = 0.5f * (Zf.y - Zg.y);
      const float Br = 0.5f * (Zf.x - Zg.x), Bi = 0.5f * (Zf.y + Zg.y);
      const float Cr = ct * Bi - st * Br, Ci = -(ct * Br + st * Bi);
      const float2 Xf = make_float2(Ar + Cr, Ai + Ci);
      const float2 Xg = make_float2(Ar - Cr, Ci - Ai);
      const float2 Yf = cmul(Xf, kerow[f]);
      const float2 Yg = cmul(Xg, kerow[g]);
      const float Pr = Yf.x + Yg.x, Pi = Yf.y - Yg.y;
      const float Qr = Yf.x - Yg.x, Qi = Yf.y + Yg.y;
      const float Rr = -(ct * Qi + st * Qr), Ri = ct * Qr - st * Qi;
      Dp[PHYS(f)] = make_float2(Pr + Rr, -(Pi + Ri));
      Dp[PHYS(g)] = make_float2(Pr - Rr, -(Ri - Pi));
    }
  }
  __syncthreads();

  {  // inverse via conj trick: data now in Dp, scratch S
    float2* tp = S; S = Dp; Dp = tp;
  }
  #pragma unroll
  for (int t = 0; t < 5; ++t) {
    fft_stage(S, Dp, tsub, 2 * t, twl);
    __syncthreads();
    float2* tp = S; S = Dp; Dp = tp;
  }

  const float Dc = Dv[c];
  u16 ov[8];
  #pragma unroll
  for (int j = 0; j < 4; ++j) {
    const float2 r = S[PHYS(4 * tsub + j)];
    const float ye = r.x + ur[2 * j] * Dc;       // ke pre-scaled by 1/2048
    const float yo = -r.y + ur[2 * j + 1] * Dc;
    ov[2 * j] = f2bf(gelu_fast(ye));
    ov[2 * j + 1] = f2bf(gelu_fast(yo));
  }
  *(u16x8*)(y + ((size_t)(b * 512 + c)) * 2048 + tsub * 8) = *(u16x8*)ov;
}

// ---------------- K2b: y (B,C,L) bf16 -> yt (B,L,C) bf16 ----------------
__global__ __launch_bounds__(256) void transpose_y(
    const u16* __restrict__ y, u16* __restrict__ yt) {
  __shared__ u16 tile[64][80];
  const int b = blockIdx.z;
  const int tb = blockIdx.x * 64;
  const int cb = blockIdx.y * 64;
  const int tid = threadIdx.x;
  {
    const int tl = (tid & 7) * 8;
    const int cl = tid >> 3;
    #pragma unroll
    for (int h = 0; h < 2; ++h) {
      const int cc = cl + h * 32;
      const u16x8 v = *(const u16x8*)(y + ((size_t)(b * 512 + cb + cc)) * 2048 + tb + tl);
      #pragma unroll
      for (int i = 0; i < 8; ++i) tile[cc][tl + i] = v[i];
    }
  }
  __syncthreads();
  {
    const int c2 = (tid & 7) * 8;
    const int t2 = tid >> 3;
    #pragma unroll
    for (int h = 0; h < 2; ++h) {
      const int tt = t2 + h * 32;
      u16 tmp[8];
      #pragma unroll
      for (int i = 0; i < 8; ++i) tmp[i] = tile[c2 + i][tt];
      *(u16x8*)(yt + ((size_t)(b * 2048 + tb + tt)) * 512 + cb + c2) = *(u16x8*)tmp;
    }
  }
}

// ---------------- K2c: W f32 -> bf16 ----------------
__global__ __launch_bounds__(256) void conv_w(const float* __restrict__ W,
                                              u16* __restrict__ Wb) {
  const int i = blockIdx.x * 256 + threadIdx.x;
  Wb[i] = f2bf(W[i]);
}

// ---------------- K3: 256x256x(K=512) 8-phase GEMM + GLU ----------------
#define FRAG_A(P, MI, S) __builtin_bit_cast(short8, *(const u16x8*)&lds[       \
    (P) * 16384 + wmh + ((MI) * 16 + lrow) * 64 + ((S) ? cs1 : cs0)])
#define FRAG_B(P, NI, S) __builtin_bit_cast(short8, *(const u16x8*)&lds[       \
    32768 + (P) * 16384 + hBh + (rB + (NI) * 16 + lrow) * 64 + ((S) ? cs1 : cs0)])

#define STAGE_A(KT, H, P) do {                                                 \
    int sr_ = m0 + (H) * 128 + wq8 + l3;                                       \
    int o0_ = (sr_ & 1) ? (512 + (sr_ >> 1)) : (sr_ >> 1);                     \
    gload_lds16(Wb + (size_t)o0_ * 512 + (KT) * 64 + csw,                      \
                lds + (P) * 16384 + (H) * 8192 + wq * 512);                    \
    sr_ += 64;                                                                 \
    int o1_ = (sr_ & 1) ? (512 + (sr_ >> 1)) : (sr_ >> 1);                     \
    gload_lds16(Wb + (size_t)o1_ * 512 + (KT) * 64 + csw,                      \
                lds + (P) * 16384 + (H) * 8192 + 4096 + wq * 512);             \
  } while (0)
#define STAGE_B(KT, H, P) do {                                                 \
    int tr_ = t0b + (H) * 128 + wq8 + l3;                                      \
    gload_lds16(yt + ((size_t)(bb * 2048 + tr_)) * 512 + (KT) * 64 + csw,      \
                lds + 32768 + (P) * 16384 + (H) * 8192 + wq * 512);            \
    gload_lds16(yt + ((size_t)(bb * 2048 + tr_ + 64)) * 512 + (KT) * 64 + csw, \
                lds + 32768 + (P) * 16384 + (H) * 8192 + 4096 + wq * 512);     \
  } while (0)

#define MFMA2(MI, NI, A0, A1)                                                  \
    acc[MI][NI] = __builtin_amdgcn_mfma_f32_16x16x32_bf16(A0, br[NI][0],       \
                                                          acc[MI][NI], 0, 0, 0); \
    acc[MI][NI] = __builtin_amdgcn_mfma_f32_16x16x32_bf16(A1, br[NI][1],       \
                                                          acc[MI][NI], 0, 0, 0);

#define PHASE_CORE(Q, READS, STAGES, VWAIT)                                    \
  {                                                                            \
    short8 a00 = FRAG_A(PP, (Q)*2 + 0, 0), a01 = FRAG_A(PP, (Q)*2 + 0, 1);     \
    short8 a10 = FRAG_A(PP, (Q)*2 + 1, 0), a11 = FRAG_A(PP, (Q)*2 + 1, 1);     \
    READS;                                                                     \
    STAGES;                                                                    \
    __builtin_amdgcn_s_barrier();                                              \
    asm volatile("s_waitcnt lgkmcnt(0)" ::: "memory");                         \
    __builtin_amdgcn_sched_barrier(0);                                         \
    __builtin_amdgcn_s_setprio(1);                                             \
    MFMA2((Q)*2 + 0, 0, a00, a01) MFMA2((Q)*2 + 0, 1, a00, a01)                \
    MFMA2((Q)*2 + 0, 2, a00, a01) MFMA2((Q)*2 + 0, 3, a00, a01)                \
    MFMA2((Q)*2 + 1, 0, a10, a11) MFMA2((Q)*2 + 1, 1, a10, a11)                \
    MFMA2((Q)*2 + 1, 2, a10, a11) MFMA2((Q)*2 + 1, 3, a10, a11)                \
    __builtin_amdgcn_s_setprio(0);                                             \
    __builtin_amdgcn_sched_barrier(0);                                         \
    VWAIT;                                                                     \
    __builtin_amdgcn_s_barrier();                                              \
  }

#define READ_B(P) do {                                                         \
    br[0][0] = FRAG_B(P, 0, 0); br[0][1] = FRAG_B(P, 0, 1);                    \
    br[1][0] = FRAG_B(P, 1, 0); br[1][1] = FRAG_B(P, 1, 1);                    \
    br[2][0] = FRAG_B(P, 2, 0); br[2][1] = FRAG_B(P, 2, 1);                    \
    br[3][0] = FRAG_B(P, 3, 0); br[3][1] = FRAG_B(P, 3, 1);                    \
  } while (0)

__global__ __launch_bounds__(512, 2) void gemm_glu(
    const u16* __restrict__ Wb, const u16* __restrict__ yt,
    const float* __restrict__ bias, float* __restrict__ out) {
  extern __shared__ __align__(16) u16 lds[];
  const int bid = blockIdx.x;
  const int wg = (bid & 7) * 64 + (bid >> 3);  // XCD swizzle (512 = 8*64)
  const int bb = wg >> 5;                      // batch
  const int mt = (wg >> 3) & 3;
  const int nt = wg & 7;
  const int m0 = mt * 256;
  const int t0b = nt * 256;
  const int tid = threadIdx.x;
  const int lane = tid & 63;
  const int wq = tid >> 6;                     // wave 0..7
  const int wq8 = wq * 8, l3 = lane >> 3;
  const int wm = wq >> 2, wn = wq & 3;
  const int lrow = lane & 15, lq = lane >> 4;
  const int csw = ((lane & 7) ^ l3) * 8;       // pre-swizzled global col
  const int cs0 = ((lq ^ (lane & 7)) << 3);
  const int cs1 = (((4 + lq) ^ (lane & 7)) << 3);
  const int wmh = wm * 8192;                   // A half base (u16)
  const int hBh = (wn >> 1) * 8192;            // B half base (u16)
  const int rB = (wn & 1) * 64;

  f32x4 acc[8][4];
  const f32x4 z4 = {0.f, 0.f, 0.f, 0.f};
  #pragma unroll
  for (int mi = 0; mi < 8; ++mi)
    #pragma unroll
    for (int ni = 0; ni < 4; ++ni) acc[mi][ni] = z4;
  short8 br[4][2];

  STAGE_A(0, 0, 0); STAGE_A(0, 1, 0);
  STAGE_B(0, 0, 0); STAGE_B(0, 1, 0);
  STAGE_B(1, 0, 1); STAGE_B(1, 1, 1);
  asm volatile("s_waitcnt vmcnt(4)" ::: "memory");
  __builtin_amdgcn_s_barrier();

  #pragma unroll
  for (int j = 0; j < 4; ++j) {
    const int e2 = 2 * j + 2, o1 = 2 * j + 1, o3 = 2 * j + 3;
    #define PP 0
    PHASE_CORE(0, READ_B(0), STAGE_A(o1, 0, 1), )
    PHASE_CORE(1, , { STAGE_A(o1, 1, 1); if (j < 3) STAGE_B(e2, 0, 0); }, )
    PHASE_CORE(2, , if (j < 3) STAGE_B(e2, 1, 0), )
    PHASE_CORE(3, , ,
               if (j < 3) { asm volatile("s_waitcnt vmcnt(4)" ::: "memory"); }
               else { asm volatile("s_waitcnt vmcnt(0)" ::: "memory"); })
    #undef PP
    #define PP 1
    PHASE_CORE(0, READ_B(1), if (j < 3) STAGE_A(e2, 0, 0), )
    PHASE_CORE(1, , if (j < 3) STAGE_A(e2, 1, 0), )
    PHASE_CORE(2, , if (j < 3) STAGE_B(o3, 0, 1), )
    PHASE_CORE(3, , if (j < 3) STAGE_B(o3, 1, 1),
               if (j < 3) { asm volatile("s_waitcnt vmcnt(4)" ::: "memory"); })
    #undef PP
  }

  #pragma unroll
  for (int mi = 0; mi < 8; ++mi) {
    const int sr0 = m0 + wm * 128 + mi * 16 + lq * 4;  // even stack row
    const int ch = sr0 >> 1;
    const float ba0 = bias[ch],     bg0 = bias[512 + ch];
    const float ba1 = bias[ch + 1], bg1 = bias[512 + ch + 1];
    #pragma unroll
    for (int ni = 0; ni < 4; ++ni) {
      const int t = t0b + wn * 64 + ni * 16 + (lane & 15);
      const f32x4 v = acc[mi][ni];
      const float a0 = v[0] + ba0, g0 = v[1] + bg0;
      const float a1 = v[2] + ba1, g1 = v[3] + bg1;
      out[((size_t)(bb * 512 + ch)) * 2048 + t]     = a0 * RCP(1.f + __expf(-g0));
      out[((size_t)(bb * 512 + ch + 1)) * 2048 + t] = a1 * RCP(1.f + __expf(-g1));
    }
  }
}

extern "C" void kernel_launch(void* const* d_in, const int* in_sizes, int n_in,
                              void* d_out, int out_size, void* d_ws, size_t ws_size,
                              hipStream_t stream) {
  (void)in_sizes; (void)n_in; (void)out_size; (void)ws_size;
  const float* u      = (const float*)d_in[0];
  const float* log_dt = (const float*)d_in[1];
  const float* Hr     = (const float*)d_in[2];
  const float* Hi     = (const float*)d_in[3];
  const float* Dv     = (const float*)d_in[4];
  const float* W      = (const float*)d_in[5];
  const float* bias   = (const float*)d_in[6];

  char* ws = (char*)d_ws;
  float2* ke = (float2*)(ws);                      // 4.2 MB
  u16*    Wb = (u16*)  (ws + ((size_t)5 << 20));   // 1 MB
  u16*    yt = (u16*)  (ws + ((size_t)8 << 20));   // 32 MB
  u16*    ybf = (u16*)d_out;                       // bf16 y staged in d_out

  build_ke<<<dim3(5, 512), 256, 0, stream>>>(log_dt, Hr, Hi, ke);
  conv_w<<<dim3(2048), 256, 0, stream>>>(W, Wb);
  fft_conv<<<dim3(8, 512), 512, 0, stream>>>(u, ke, Dv, ybf);
  transpose_y<<<dim3(32, 8, 16), 256, 0, stream>>>(ybf, yt);
  gemm_glu<<<dim3(512), 512, 131072, stream>>>(Wb, yt, bias, (float*)d_out);
}